// Round 2
// baseline (907.111 us; speedup 1.0000x reference)
//
#include <hip/hip_runtime.h>
#include <hip/hip_bf16.h>

#define N_LOC 500000
#define C 128
#define A 24
#define AC 152          // A + C
#define H 256
#define X 128
#define G3 768          // 3*H

__device__ __forceinline__ float sigmoidf_(float x) { return 1.0f / (1.0f + __expf(-x)); }

// ---------------------------------------------------------------------------
// Big streaming pass over the N_LOC x C memory.
// UPDATE=false: step-1 similarity only: e = exp(beta*sim(mem)), craw += e*mem
// UPDATE=true : apply erase/cand write for step t, then sim/e/craw for step t+1
// STORE : whether the updated memory must be written back (skipped on last pass)
// ---------------------------------------------------------------------------
template <bool UPDATE, bool STORE>
__global__ __launch_bounds__(256) void big_pass(
    float* __restrict__ mem, const float* __restrict__ addr,
    const float* __restrict__ qacc,   // [153]: q[0..151], raw sharpen at [152]
    const float* __restrict__ eacc,   // [128] raw erase pre-sigmoid
    const float* __restrict__ cacc,   // [128] raw cand pre-relu
    const float* __restrict__ invp,   // 1/sum_e of previous softmax
    float* __restrict__ e,            // [N_LOC]
    float* __restrict__ craw)         // [129] atomic accumulator (content | sum)
{
    const int lane = threadIdx.x & 31;   // column group: 4 floats each
    const int rg   = threadIdx.x >> 5;   // row group 0..7

    // per-lane constants
    const float4 qc = *(const float4*)(qacc + A + 4 * lane);
    float4 qa = make_float4(0.f, 0.f, 0.f, 0.f);
    if (lane < 6) qa = *(const float4*)(qacc + 4 * lane);
    float beta;
    { float t = qacc[AC]; beta = (t > 20.f ? t : log1pf(__expf(t))) + 1.0f; }

    float4 er = make_float4(0.f, 0.f, 0.f, 0.f);
    float4 cd = make_float4(0.f, 0.f, 0.f, 0.f);
    float inv_sum = 0.f;
    if (UPDATE) {
        float4 et = *(const float4*)(eacc + 4 * lane);
        er.x = sigmoidf_(et.x); er.y = sigmoidf_(et.y);
        er.z = sigmoidf_(et.z); er.w = sigmoidf_(et.w);
        float4 ct = *(const float4*)(cacc + 4 * lane);
        cd.x = fmaxf(ct.x, 0.f); cd.y = fmaxf(ct.y, 0.f);
        cd.z = fmaxf(ct.z, 0.f); cd.w = fmaxf(ct.w, 0.f);
        inv_sum = *invp;
    }

    float4 acc = make_float4(0.f, 0.f, 0.f, 0.f);
    float sumloc = 0.f;
    const int stride = gridDim.x * 8;

    for (int i = blockIdx.x * 8 + rg; i < N_LOC; i += stride) {
        float4 m = *(const float4*)(mem + (size_t)i * C + 4 * lane);
        if (UPDATE) {
            float w = e[i] * inv_sum;
            m.x = m.x * (1.f - w * er.x) + w * cd.x;
            m.y = m.y * (1.f - w * er.y) + w * cd.y;
            m.z = m.z * (1.f - w * er.z) + w * cd.z;
            m.w = m.w * (1.f - w * er.w) + w * cd.w;
            if (STORE) *(float4*)(mem + (size_t)i * C + 4 * lane) = m;
        }
        float s = m.x * qc.x + m.y * qc.y + m.z * qc.z + m.w * qc.w;
        if (lane < 6) {
            float4 a4 = *(const float4*)(addr + (size_t)i * A + 4 * lane);
            s += a4.x * qa.x + a4.y * qa.y + a4.z * qa.z + a4.w * qa.w;
        }
        // butterfly reduce across the 32-lane group (all lanes get the sum)
        s += __shfl_xor(s, 1);
        s += __shfl_xor(s, 2);
        s += __shfl_xor(s, 4);
        s += __shfl_xor(s, 8);
        s += __shfl_xor(s, 16);
        float ev = __expf(beta * s);
        if (lane == 0) { e[i] = ev; sumloc += ev; }
        acc.x += ev * m.x; acc.y += ev * m.y;
        acc.z += ev * m.z; acc.w += ev * m.w;
    }

    __shared__ float sc[8][C];
    __shared__ float ssum[256];
    *(float4*)(&sc[rg][4 * lane]) = acc;
    ssum[threadIdx.x] = sumloc;
    __syncthreads();
    if (threadIdx.x < C) {
        float v = 0.f;
#pragma unroll
        for (int g = 0; g < 8; ++g) v += sc[g][threadIdx.x];
        atomicAdd(craw + threadIdx.x, v);
    }
    for (int off = 128; off > 0; off >>= 1) {
        if (threadIdx.x < off) ssum[threadIdx.x] += ssum[threadIdx.x + off];
        __syncthreads();
    }
    if (threadIdx.x == 0) atomicAdd(craw + C, ssum[0]);
}

// ---------------------------------------------------------------------------
// Once per launch: gix = x @ W_ih[0:128] + b_ih ; candx = x @ W_cand_x
// grid 16, k-sliced (8 rows of x each), atomic accumulate.
// ---------------------------------------------------------------------------
__global__ __launch_bounds__(256) void prex(
    const float* __restrict__ x, const float* __restrict__ W_ih,
    const float* __restrict__ b_ih, const float* __restrict__ W_cx,
    float* __restrict__ gix, float* __restrict__ candx)
{
    const int tid = threadIdx.x;
    float a0 = 0.f, a1 = 0.f, a2 = 0.f, ac = 0.f;
    const int k0 = blockIdx.x * 8;
    for (int k = k0; k < k0 + 8; ++k) {
        float xk = x[k];
        const float* row = W_ih + (size_t)k * G3;
        a0 += xk * row[tid];
        a1 += xk * row[256 + tid];
        a2 += xk * row[512 + tid];
        if (tid < C) ac += xk * W_cx[k * C + tid];
    }
    const bool b0 = (blockIdx.x == 0);
    atomicAdd(gix + tid,        a0 + (b0 ? b_ih[tid] : 0.f));
    atomicAdd(gix + 256 + tid,  a1 + (b0 ? b_ih[256 + tid] : 0.f));
    atomicAdd(gix + 512 + tid,  a2 + (b0 ? b_ih[512 + tid] : 0.f));
    if (tid < C) atomicAdd(candx + tid, ac);
}

// ---------------------------------------------------------------------------
// Per step: raw erase/cand/query/sharpen projections from h.
// grid 16, k-sliced (16 rows of h each). Nonlinearities applied by consumer.
// ---------------------------------------------------------------------------
__global__ __launch_bounds__(256) void post(
    const float* __restrict__ h,
    const float* __restrict__ W_er, const float* __restrict__ b_er,
    const float* __restrict__ W_ch, const float* __restrict__ b_cd,
    const float* __restrict__ W_q,  const float* __restrict__ b_q,
    const float* __restrict__ u_sh, const float* __restrict__ b_sh,
    const float* __restrict__ candx,
    float* __restrict__ eacc, float* __restrict__ cacc, float* __restrict__ qacc)
{
    const int tid = threadIdx.x;
    float ae = 0.f, ac = 0.f, aq = 0.f, ab = 0.f;
    const int k0 = blockIdx.x * 16;
    for (int k = k0; k < k0 + 16; ++k) {
        float hk = h[k];
        if (tid < C)  { ae += hk * W_er[k * C + tid]; ac += hk * W_ch[k * C + tid]; }
        if (tid < AC)   aq += hk * W_q[k * AC + tid];
        if (tid == 255) ab += hk * u_sh[k];
    }
    const bool b0 = (blockIdx.x == 0);
    if (tid < C) {
        atomicAdd(eacc + tid, ae + (b0 ? b_er[tid] : 0.f));
        atomicAdd(cacc + tid, ac + (b0 ? (candx[tid] + b_cd[tid]) : 0.f));
    }
    if (tid < AC)   atomicAdd(qacc + tid, aq + (b0 ? b_q[tid] : 0.f));
    if (tid == 255) atomicAdd(qacc + AC, ab + (b0 ? b_sh[0] : 0.f));
}

// ---------------------------------------------------------------------------
// Per step: GRU gate pre-activations. gacc[0:768] = gi (content part + gix),
// gacc[768:1536] = gh. grid 16, k-sliced.
// ---------------------------------------------------------------------------
__global__ __launch_bounds__(256) void gates(
    const float* __restrict__ craw, const float* __restrict__ hprev,
    const float* __restrict__ W_ih, const float* __restrict__ W_hh,
    const float* __restrict__ b_hh, const float* __restrict__ gix,
    float* __restrict__ gacc)
{
    const int tid = threadIdx.x;
    const float inv = 1.0f / craw[C];
    float gi0 = 0.f, gi1 = 0.f, gi2 = 0.f, gh0 = 0.f, gh1 = 0.f, gh2 = 0.f;
    const int kc0 = blockIdx.x * 8;
    for (int k = kc0; k < kc0 + 8; ++k) {
        float ck = craw[k] * inv;                       // content[k]
        const float* row = W_ih + (size_t)(X + k) * G3;
        gi0 += ck * row[tid]; gi1 += ck * row[256 + tid]; gi2 += ck * row[512 + tid];
    }
    const int kh0 = blockIdx.x * 16;
    for (int k = kh0; k < kh0 + 16; ++k) {
        float hk = hprev[k];
        const float* row = W_hh + (size_t)k * G3;
        gh0 += hk * row[tid]; gh1 += hk * row[256 + tid]; gh2 += hk * row[512 + tid];
    }
    const bool b0 = (blockIdx.x == 0);
    atomicAdd(gacc + tid,              gi0 + (b0 ? gix[tid] : 0.f));
    atomicAdd(gacc + 256 + tid,        gi1 + (b0 ? gix[256 + tid] : 0.f));
    atomicAdd(gacc + 512 + tid,        gi2 + (b0 ? gix[512 + tid] : 0.f));
    atomicAdd(gacc + G3 + tid,         gh0 + (b0 ? b_hh[tid] : 0.f));
    atomicAdd(gacc + G3 + 256 + tid,   gh1 + (b0 ? b_hh[256 + tid] : 0.f));
    atomicAdd(gacc + G3 + 512 + tid,   gh2 + (b0 ? b_hh[512 + tid] : 0.f));
}

// ---------------------------------------------------------------------------
// Per step: GRU combine -> h (written to d_out); saves 1/sum_e; zeroes
// gacc + craw for the next step's accumulation.
// ---------------------------------------------------------------------------
__global__ __launch_bounds__(256) void fin(
    float* gacc, const float* __restrict__ hprev,
    float* __restrict__ hout, float* craw, float* __restrict__ invp)
{
    const int j = threadIdx.x;
    float ir = gacc[j], iz = gacc[256 + j], in_ = gacc[512 + j];
    float hr = gacc[G3 + j], hz = gacc[G3 + 256 + j], hn = gacc[G3 + 512 + j];
    float r = sigmoidf_(ir + hr);
    float z = sigmoidf_(iz + hz);
    float n = tanhf(in_ + r * hn);
    float hp = hprev[j];
    hout[j] = (1.f - z) * n + z * hp;
    if (j == 0) *invp = 1.0f / craw[C];
    __syncthreads();
    gacc[j] = 0.f; gacc[256 + j] = 0.f; gacc[512 + j] = 0.f;
    gacc[G3 + j] = 0.f; gacc[G3 + 256 + j] = 0.f; gacc[G3 + 512 + j] = 0.f;
    if (j <= C) craw[j] = 0.f;   // 129 entries
}

extern "C" void kernel_launch(void* const* d_in, const int* in_sizes, int n_in,
                              void* d_out, int out_size, void* d_ws, size_t ws_size,
                              hipStream_t stream) {
    (void)in_sizes; (void)n_in; (void)out_size; (void)ws_size;
    const float* x    = (const float*)d_in[0];
    const float* h0   = (const float*)d_in[1];
    float*       mem  = (float*)d_in[2];   // updated in place; harness restores
    const float* addr = (const float*)d_in[3];
    const float* W_q  = (const float*)d_in[4];
    const float* b_q  = (const float*)d_in[5];
    const float* u_sh = (const float*)d_in[6];
    const float* b_sh = (const float*)d_in[7];
    const float* W_er = (const float*)d_in[8];
    const float* b_er = (const float*)d_in[9];
    const float* W_ch = (const float*)d_in[10];
    const float* W_cx = (const float*)d_in[11];
    const float* b_cd = (const float*)d_in[12];
    const float* W_ih = (const float*)d_in[13];
    const float* W_hh = (const float*)d_in[14];
    const float* b_ih = (const float*)d_in[15];
    const float* b_hh = (const float*)d_in[16];
    // d_in[17] = num_addressing_steps == 4 (constant; loop unrolled host-side)
    float* hout = (float*)d_out;

    // workspace layout (floats):
    float* e     = (float*)d_ws;         // [N_LOC]
    float* S     = e + N_LOC;            // scalar/accumulator region
    float* craw  = S;                    // [129] (padded to 144)
    float* gacc  = S + 144;              // [1536]
    float* eacc  = S + 1680;             // [128]
    float* cacc  = S + 1808;             // [128]
    float* qacc  = S + 1936;             // [153] (eacc/cacc/qacc contiguous: 409)
    float* gix   = S + 2096;             // [768]
    float* candx = S + 2864;             // [128]
    float* invp  = S + 2992;             // [1]

    hipMemsetAsync(S, 0, 3000 * sizeof(float), stream);
    prex<<<16, 256, 0, stream>>>(x, W_ih, b_ih, W_cx, gix, candx);
    post<<<16, 256, 0, stream>>>(h0, W_er, b_er, W_ch, b_cd, W_q, b_q, u_sh, b_sh,
                                 candx, eacc, cacc, qacc);
    big_pass<false, false><<<1024, 256, 0, stream>>>(mem, addr, qacc, eacc, cacc,
                                                     invp, e, craw);
    for (int t = 1; t <= 4; ++t) {
        const float* hprev = (t == 1) ? h0 : hout;
        gates<<<16, 256, 0, stream>>>(craw, hprev, W_ih, W_hh, b_hh, gix, gacc);
        fin<<<1, 256, 0, stream>>>(gacc, hprev, hout, craw, invp);
        if (t < 4) {
            hipMemsetAsync(eacc, 0, 409 * sizeof(float), stream);
            post<<<16, 256, 0, stream>>>(hout, W_er, b_er, W_ch, b_cd, W_q, b_q,
                                         u_sh, b_sh, candx, eacc, cacc, qacc);
            if (t < 3)
                big_pass<true, true><<<1024, 256, 0, stream>>>(mem, addr, qacc, eacc,
                                                               cacc, invp, e, craw);
            else
                big_pass<true, false><<<1024, 256, 0, stream>>>(mem, addr, qacc, eacc,
                                                                cacc, invp, e, craw);
        }
    }
}

// Round 3
// 825.882 us; speedup vs baseline: 1.0984x; 1.0984x over previous
//
#include <hip/hip_runtime.h>
#include <hip/hip_bf16.h>

#define N_LOC 500000
#define C 128
#define A 24
#define AC 152          // A + C
#define H 256
#define X 128
#define G3 768          // 3*H
#define GRID_BIG 1024

__device__ __forceinline__ float sigmoidf_(float x) { return 1.0f / (1.0f + __expf(-x)); }

// ---------------------------------------------------------------------------
// Big streaming pass over the N_LOC x C memory (mem0 is NEVER written).
// mem_t is recomputed on the fly: for s=1..NPREV,
//   w_s[i] = e_s[i]/sum_s ; m = m*(1 - w_s*er_s) + w_s*cd_s
// Then similarity for the current step's query, e = exp(beta*sim),
// unnormalized content accumulated into per-block partials (no atomics).
// ---------------------------------------------------------------------------
template <int NPREV, bool WRITE_E>
__global__ __launch_bounds__(256) void big_pass(
    const float* __restrict__ mem0, const float* __restrict__ addr,
    const float* __restrict__ qacc,   // [153]: q[0..151], raw sharpen at [152]
    const float* __restrict__ ehist,  // [4][128] raw erase pre-sigmoid (slot s)
    const float* __restrict__ chist,  // [4][128] raw cand pre-relu
    const float* __restrict__ ssum4,  // [8]: ssum4[s] = softmax denom of step s
    const float* __restrict__ earr,   // [3][N_LOC] raw exp values per step
    float* __restrict__ enew,         // e output for this step (if WRITE_E)
    float* __restrict__ part)         // [GRID_BIG][132] partials (content|sum)
{
    const int lane = threadIdx.x & 31;   // column group: 4 floats each
    const int rg   = threadIdx.x >> 5;   // row group 0..7

    // per-lane constants
    const float4 qc = *(const float4*)(qacc + A + 4 * lane);
    float4 qa = make_float4(0.f, 0.f, 0.f, 0.f);
    if (lane < 6) qa = *(const float4*)(qacc + 4 * lane);
    float beta;
    { float t = qacc[AC]; beta = (t > 20.f ? t : log1pf(__expf(t))) + 1.0f; }

    constexpr int NP = (NPREV > 0) ? NPREV : 1;
    float4 er[NP], cd[NP];
    float inv_s[NP];
#pragma unroll
    for (int s = 0; s < NPREV; ++s) {
        float4 et = *(const float4*)(ehist + (s + 1) * C + 4 * lane);
        er[s].x = sigmoidf_(et.x); er[s].y = sigmoidf_(et.y);
        er[s].z = sigmoidf_(et.z); er[s].w = sigmoidf_(et.w);
        float4 ct = *(const float4*)(chist + (s + 1) * C + 4 * lane);
        cd[s].x = fmaxf(ct.x, 0.f); cd[s].y = fmaxf(ct.y, 0.f);
        cd[s].z = fmaxf(ct.z, 0.f); cd[s].w = fmaxf(ct.w, 0.f);
        inv_s[s] = 1.0f / ssum4[s + 1];
    }

    float4 acc = make_float4(0.f, 0.f, 0.f, 0.f);
    float sumloc = 0.f;
    const int stride = gridDim.x * 8;

    for (int i = blockIdx.x * 8 + rg; i < N_LOC; i += stride) {
        float w_s[NP];
#pragma unroll
        for (int s = 0; s < NPREV; ++s)
            w_s[s] = earr[s * N_LOC + i] * inv_s[s];

        float4 m = *(const float4*)(mem0 + (size_t)i * C + 4 * lane);
#pragma unroll
        for (int s = 0; s < NPREV; ++s) {
            float w = w_s[s];
            m.x = m.x * (1.f - w * er[s].x) + w * cd[s].x;
            m.y = m.y * (1.f - w * er[s].y) + w * cd[s].y;
            m.z = m.z * (1.f - w * er[s].z) + w * cd[s].z;
            m.w = m.w * (1.f - w * er[s].w) + w * cd[s].w;
        }

        float s = m.x * qc.x + m.y * qc.y + m.z * qc.z + m.w * qc.w;
        if (lane < 6) {
            float4 a4 = *(const float4*)(addr + (size_t)i * A + 4 * lane);
            s += a4.x * qa.x + a4.y * qa.y + a4.z * qa.z + a4.w * qa.w;
        }
        // butterfly reduce across the 32-lane group (all lanes get the sum)
        s += __shfl_xor(s, 1);
        s += __shfl_xor(s, 2);
        s += __shfl_xor(s, 4);
        s += __shfl_xor(s, 8);
        s += __shfl_xor(s, 16);
        float ev = __expf(beta * s);
        if (WRITE_E && lane == 0) enew[i] = ev;
        if (lane == 0) sumloc += ev;
        acc.x += ev * m.x; acc.y += ev * m.y;
        acc.z += ev * m.z; acc.w += ev * m.w;
    }

    __shared__ float sc[8][C];
    __shared__ float ssum[256];
    *(float4*)(&sc[rg][4 * lane]) = acc;
    ssum[threadIdx.x] = sumloc;
    __syncthreads();
    if (threadIdx.x < C) {
        float v = 0.f;
#pragma unroll
        for (int g = 0; g < 8; ++g) v += sc[g][threadIdx.x];
        part[blockIdx.x * 132 + threadIdx.x] = v;
    }
    for (int off = 128; off > 0; off >>= 1) {
        if (threadIdx.x < off) ssum[threadIdx.x] += ssum[threadIdx.x + off];
        __syncthreads();
    }
    if (threadIdx.x == 0) part[blockIdx.x * 132 + C] = ssum[0];
}

// ---------------------------------------------------------------------------
// Reduce the GRID_BIG x 129 partials -> craw[0..128]; also record this step's
// softmax denominator in ssum4[step]. Partials live in L2 (528 KB).
// ---------------------------------------------------------------------------
__global__ __launch_bounds__(256) void reduce_part(
    const float* __restrict__ part, float* __restrict__ craw,
    float* __restrict__ ssum4, int step)
{
    const int j = blockIdx.x;           // 0..128
    float v = 0.f;
    for (int b = threadIdx.x; b < GRID_BIG; b += 256)
        v += part[b * 132 + j];
    __shared__ float sh[256];
    sh[threadIdx.x] = v;
    __syncthreads();
    for (int off = 128; off > 0; off >>= 1) {
        if (threadIdx.x < off) sh[threadIdx.x] += sh[threadIdx.x + off];
        __syncthreads();
    }
    if (threadIdx.x == 0) {
        craw[j] = sh[0];
        if (j == C) ssum4[step] = sh[0];
    }
}

// ---------------------------------------------------------------------------
// Once per launch: gix = x @ W_ih[0:128] + b_ih ; candx = x @ W_cand_x
// ---------------------------------------------------------------------------
__global__ __launch_bounds__(256) void prex(
    const float* __restrict__ x, const float* __restrict__ W_ih,
    const float* __restrict__ b_ih, const float* __restrict__ W_cx,
    float* __restrict__ gix, float* __restrict__ candx)
{
    const int tid = threadIdx.x;
    float a0 = 0.f, a1 = 0.f, a2 = 0.f, ac = 0.f;
    const int k0 = blockIdx.x * 8;
    for (int k = k0; k < k0 + 8; ++k) {
        float xk = x[k];
        const float* row = W_ih + (size_t)k * G3;
        a0 += xk * row[tid];
        a1 += xk * row[256 + tid];
        a2 += xk * row[512 + tid];
        if (tid < C) ac += xk * W_cx[k * C + tid];
    }
    const bool b0 = (blockIdx.x == 0);
    atomicAdd(gix + tid,        a0 + (b0 ? b_ih[tid] : 0.f));
    atomicAdd(gix + 256 + tid,  a1 + (b0 ? b_ih[256 + tid] : 0.f));
    atomicAdd(gix + 512 + tid,  a2 + (b0 ? b_ih[512 + tid] : 0.f));
    if (tid < C) atomicAdd(candx + tid, ac);
}

// ---------------------------------------------------------------------------
// Per step: raw erase/cand/query/sharpen projections from h into history
// slots + qacc. Nonlinearities applied by the consumer (big_pass).
// ---------------------------------------------------------------------------
__global__ __launch_bounds__(256) void post(
    const float* __restrict__ h,
    const float* __restrict__ W_er, const float* __restrict__ b_er,
    const float* __restrict__ W_ch, const float* __restrict__ b_cd,
    const float* __restrict__ W_q,  const float* __restrict__ b_q,
    const float* __restrict__ u_sh, const float* __restrict__ b_sh,
    const float* __restrict__ candx,
    float* __restrict__ eslot, float* __restrict__ cslot,
    float* __restrict__ qacc)
{
    const int tid = threadIdx.x;
    float ae = 0.f, ac = 0.f, aq = 0.f, ab = 0.f;
    const int k0 = blockIdx.x * 16;
    for (int k = k0; k < k0 + 16; ++k) {
        float hk = h[k];
        if (tid < C)  { ae += hk * W_er[k * C + tid]; ac += hk * W_ch[k * C + tid]; }
        if (tid < AC)   aq += hk * W_q[k * AC + tid];
        if (tid == 255) ab += hk * u_sh[k];
    }
    const bool b0 = (blockIdx.x == 0);
    if (tid < C) {
        atomicAdd(eslot + tid, ae + (b0 ? b_er[tid] : 0.f));
        atomicAdd(cslot + tid, ac + (b0 ? (candx[tid] + b_cd[tid]) : 0.f));
    }
    if (tid < AC)   atomicAdd(qacc + tid, aq + (b0 ? b_q[tid] : 0.f));
    if (tid == 255) atomicAdd(qacc + AC, ab + (b0 ? b_sh[0] : 0.f));
}

// ---------------------------------------------------------------------------
// Per step: GRU gate pre-activations. gacc[0:768] = gi (content part + gix),
// gacc[768:1536] = gh. grid 16, k-sliced.
// ---------------------------------------------------------------------------
__global__ __launch_bounds__(256) void gates(
    const float* __restrict__ craw, const float* __restrict__ hprev,
    const float* __restrict__ W_ih, const float* __restrict__ W_hh,
    const float* __restrict__ b_hh, const float* __restrict__ gix,
    float* __restrict__ gacc)
{
    const int tid = threadIdx.x;
    const float inv = 1.0f / craw[C];
    float gi0 = 0.f, gi1 = 0.f, gi2 = 0.f, gh0 = 0.f, gh1 = 0.f, gh2 = 0.f;
    const int kc0 = blockIdx.x * 8;
    for (int k = kc0; k < kc0 + 8; ++k) {
        float ck = craw[k] * inv;                       // content[k]
        const float* row = W_ih + (size_t)(X + k) * G3;
        gi0 += ck * row[tid]; gi1 += ck * row[256 + tid]; gi2 += ck * row[512 + tid];
    }
    const int kh0 = blockIdx.x * 16;
    for (int k = kh0; k < kh0 + 16; ++k) {
        float hk = hprev[k];
        const float* row = W_hh + (size_t)k * G3;
        gh0 += hk * row[tid]; gh1 += hk * row[256 + tid]; gh2 += hk * row[512 + tid];
    }
    const bool b0 = (blockIdx.x == 0);
    atomicAdd(gacc + tid,              gi0 + (b0 ? gix[tid] : 0.f));
    atomicAdd(gacc + 256 + tid,        gi1 + (b0 ? gix[256 + tid] : 0.f));
    atomicAdd(gacc + 512 + tid,        gi2 + (b0 ? gix[512 + tid] : 0.f));
    atomicAdd(gacc + G3 + tid,         gh0 + (b0 ? b_hh[tid] : 0.f));
    atomicAdd(gacc + G3 + 256 + tid,   gh1 + (b0 ? b_hh[256 + tid] : 0.f));
    atomicAdd(gacc + G3 + 512 + tid,   gh2 + (b0 ? b_hh[512 + tid] : 0.f));
}

// ---------------------------------------------------------------------------
// Per step: GRU combine -> h (written to d_out); zeroes gacc + qacc for the
// next step's atomic accumulation.
// ---------------------------------------------------------------------------
__global__ __launch_bounds__(256) void fin(
    float* gacc, const float* __restrict__ hprev,
    float* __restrict__ hout, float* __restrict__ qacc)
{
    const int j = threadIdx.x;
    float ir = gacc[j], iz = gacc[256 + j], in_ = gacc[512 + j];
    float hr = gacc[G3 + j], hz = gacc[G3 + 256 + j], hn = gacc[G3 + 512 + j];
    float r = sigmoidf_(ir + hr);
    float z = sigmoidf_(iz + hz);
    float n = tanhf(in_ + r * hn);
    float hp = hprev[j];
    hout[j] = (1.f - z) * n + z * hp;
    gacc[j] = 0.f; gacc[256 + j] = 0.f; gacc[512 + j] = 0.f;
    gacc[G3 + j] = 0.f; gacc[G3 + 256 + j] = 0.f; gacc[G3 + 512 + j] = 0.f;
    if (j < 160) qacc[j] = 0.f;
}

extern "C" void kernel_launch(void* const* d_in, const int* in_sizes, int n_in,
                              void* d_out, int out_size, void* d_ws, size_t ws_size,
                              hipStream_t stream) {
    (void)in_sizes; (void)n_in; (void)out_size; (void)ws_size;
    const float* x    = (const float*)d_in[0];
    const float* h0   = (const float*)d_in[1];
    const float* mem0 = (const float*)d_in[2];   // read-only now
    const float* addr = (const float*)d_in[3];
    const float* W_q  = (const float*)d_in[4];
    const float* b_q  = (const float*)d_in[5];
    const float* u_sh = (const float*)d_in[6];
    const float* b_sh = (const float*)d_in[7];
    const float* W_er = (const float*)d_in[8];
    const float* b_er = (const float*)d_in[9];
    const float* W_ch = (const float*)d_in[10];
    const float* W_cx = (const float*)d_in[11];
    const float* b_cd = (const float*)d_in[12];
    const float* W_ih = (const float*)d_in[13];
    const float* W_hh = (const float*)d_in[14];
    const float* b_ih = (const float*)d_in[15];
    const float* b_hh = (const float*)d_in[16];
    // d_in[17] = num_addressing_steps == 4 (constant; loop unrolled host-side)
    float* hout = (float*)d_out;

    // workspace layout (floats):
    float* e     = (float*)d_ws;              // [3][N_LOC] raw exps, steps 1..3
    float* part  = e + 3 * N_LOC;             // [GRID_BIG][132]
    float* S     = part + GRID_BIG * 132;     // small accumulator region
    float* craw  = S;                         // [132]
    float* gacc  = S + 144;                   // [1536]
    float* qacc  = S + 1680;                  // [160] (153 used)
    float* ehist = S + 1840;                  // [4][128]
    float* chist = S + 2352;                  // [4][128]
    float* gix   = S + 2864;                  // [768]
    float* candx = S + 3632;                  // [128]
    float* ssum4 = S + 3760;                  // [8]
    // total S: 3768 floats

    hipMemsetAsync(S, 0, 3768 * sizeof(float), stream);
    prex<<<16, 256, 0, stream>>>(x, W_ih, b_ih, W_cx, gix, candx);
    // post(h0): qacc for step 1; ehist/chist slot 0 are never consumed
    post<<<16, 256, 0, stream>>>(h0, W_er, b_er, W_ch, b_cd, W_q, b_q, u_sh, b_sh,
                                 candx, ehist, chist, qacc);
    big_pass<0, true><<<GRID_BIG, 256, 0, stream>>>(mem0, addr, qacc, ehist, chist,
                                                    ssum4, e, e, part);
    reduce_part<<<129, 256, 0, stream>>>(part, craw, ssum4, 1);

    // step 1
    gates<<<16, 256, 0, stream>>>(craw, h0, W_ih, W_hh, b_hh, gix, gacc);
    fin<<<1, 256, 0, stream>>>(gacc, h0, hout, qacc);
    post<<<16, 256, 0, stream>>>(hout, W_er, b_er, W_ch, b_cd, W_q, b_q, u_sh, b_sh,
                                 candx, ehist + C, chist + C, qacc);
    big_pass<1, true><<<GRID_BIG, 256, 0, stream>>>(mem0, addr, qacc, ehist, chist,
                                                    ssum4, e, e + N_LOC, part);
    reduce_part<<<129, 256, 0, stream>>>(part, craw, ssum4, 2);

    // step 2
    gates<<<16, 256, 0, stream>>>(craw, hout, W_ih, W_hh, b_hh, gix, gacc);
    fin<<<1, 256, 0, stream>>>(gacc, hout, hout, qacc);
    post<<<16, 256, 0, stream>>>(hout, W_er, b_er, W_ch, b_cd, W_q, b_q, u_sh, b_sh,
                                 candx, ehist + 2 * C, chist + 2 * C, qacc);
    big_pass<2, true><<<GRID_BIG, 256, 0, stream>>>(mem0, addr, qacc, ehist, chist,
                                                    ssum4, e, e + 2 * N_LOC, part);
    reduce_part<<<129, 256, 0, stream>>>(part, craw, ssum4, 3);

    // step 3
    gates<<<16, 256, 0, stream>>>(craw, hout, W_ih, W_hh, b_hh, gix, gacc);
    fin<<<1, 256, 0, stream>>>(gacc, hout, hout, qacc);
    post<<<16, 256, 0, stream>>>(hout, W_er, b_er, W_ch, b_cd, W_q, b_q, u_sh, b_sh,
                                 candx, ehist + 3 * C, chist + 3 * C, qacc);
    big_pass<3, false><<<GRID_BIG, 256, 0, stream>>>(mem0, addr, qacc, ehist, chist,
                                                     ssum4, e, e, part);
    reduce_part<<<129, 256, 0, stream>>>(part, craw, ssum4, 4);

    // step 4
    gates<<<16, 256, 0, stream>>>(craw, hout, W_ih, W_hh, b_hh, gix, gacc);
    fin<<<1, 256, 0, stream>>>(gacc, hout, hout, qacc);
}

// Round 4
// 753.679 us; speedup vs baseline: 1.2036x; 1.0958x over previous
//
#include <hip/hip_runtime.h>
#include <hip/hip_bf16.h>

#define N_LOC 500000
#define C 128
#define A 24
#define AC 152          // A + C
#define H 256
#define X 128
#define G3 768          // 3*H
#define GRID_BIG 1024

typedef unsigned short ushort_t;

__device__ __forceinline__ float sigmoidf_(float x) { return 1.0f / (1.0f + __expf(-x)); }

// bf16 pack/unpack (round-to-nearest-even; inputs are finite)
__device__ __forceinline__ ushort_t f2bf(float f) {
    unsigned u = __float_as_uint(f);
    u += 0x7FFFu + ((u >> 16) & 1u);
    return (ushort_t)(u >> 16);
}
__device__ __forceinline__ float bf2f(ushort_t s) {
    return __uint_as_float(((unsigned)s) << 16);
}

// ---------------------------------------------------------------------------
// Big streaming pass over the N_LOC x C memory (mem0 is NEVER written).
// mem_t recomputed on the fly from pristine mem0 + per-step scalars e_s[i]
// and 128-vectors er_s/cd_s. Then sim/e for the current query, unnormalized
// content into per-block partials (no global atomics).
// CONVERT (pass 1 only): reads fp32 mem0/addr and emits bf16 copies;
// otherwise reads the bf16 copies.
// ---------------------------------------------------------------------------
template <int NPREV, bool WRITE_E, bool CONVERT>
__global__ __launch_bounds__(256) void big_pass(
    const float* __restrict__ mem0, const float* __restrict__ addr,
    ushort_t* __restrict__ membf, ushort_t* __restrict__ addrbf,
    const float* __restrict__ qacc,   // [153]: q[0..151], raw sharpen at [152]
    const float* __restrict__ ehist,  // [4][128] raw erase pre-sigmoid
    const float* __restrict__ chist,  // [4][128] raw cand pre-relu
    const float* __restrict__ ssum4,  // [8]: softmax denom of step s
    const float* __restrict__ earr,   // [3][N_LOC] raw exp values per step
    float* __restrict__ enew,         // e output for this step (if WRITE_E)
    float* __restrict__ part)         // [GRID_BIG][132] partials (content|sum)
{
    const int lane = threadIdx.x & 31;   // column group: 4 floats each
    const int rg   = threadIdx.x >> 5;   // row group 0..7

    const float4 qc = *(const float4*)(qacc + A + 4 * lane);
    float4 qa = make_float4(0.f, 0.f, 0.f, 0.f);
    if (lane < 6) qa = *(const float4*)(qacc + 4 * lane);
    float beta;
    { float t = qacc[AC]; beta = (t > 20.f ? t : log1pf(__expf(t))) + 1.0f; }

    constexpr int NP = (NPREV > 0) ? NPREV : 1;
    float4 er[NP], cd[NP];
    float inv_s[NP];
#pragma unroll
    for (int s = 0; s < NPREV; ++s) {
        float4 et = *(const float4*)(ehist + (s + 1) * C + 4 * lane);
        er[s].x = sigmoidf_(et.x); er[s].y = sigmoidf_(et.y);
        er[s].z = sigmoidf_(et.z); er[s].w = sigmoidf_(et.w);
        float4 ct = *(const float4*)(chist + (s + 1) * C + 4 * lane);
        cd[s].x = fmaxf(ct.x, 0.f); cd[s].y = fmaxf(ct.y, 0.f);
        cd[s].z = fmaxf(ct.z, 0.f); cd[s].w = fmaxf(ct.w, 0.f);
        inv_s[s] = 1.0f / ssum4[s + 1];
    }

    float4 acc = make_float4(0.f, 0.f, 0.f, 0.f);
    float sumloc = 0.f;
    const int stride = gridDim.x * 8;

    for (int i = blockIdx.x * 8 + rg; i < N_LOC; i += stride) {
        float4 m, a4 = make_float4(0.f, 0.f, 0.f, 0.f);
        if (CONVERT) {
            m = *(const float4*)(mem0 + (size_t)i * C + 4 * lane);
            ushort4 mu; mu.x = f2bf(m.x); mu.y = f2bf(m.y);
            mu.z = f2bf(m.z); mu.w = f2bf(m.w);
            *(ushort4*)(membf + (size_t)i * C + 4 * lane) = mu;
            if (lane < 6) {
                a4 = *(const float4*)(addr + (size_t)i * A + 4 * lane);
                ushort4 au; au.x = f2bf(a4.x); au.y = f2bf(a4.y);
                au.z = f2bf(a4.z); au.w = f2bf(a4.w);
                *(ushort4*)(addrbf + (size_t)i * A + 4 * lane) = au;
            }
        } else {
            ushort4 mu = *(const ushort4*)(membf + (size_t)i * C + 4 * lane);
            m = make_float4(bf2f(mu.x), bf2f(mu.y), bf2f(mu.z), bf2f(mu.w));
            if (lane < 6) {
                ushort4 au = *(const ushort4*)(addrbf + (size_t)i * A + 4 * lane);
                a4 = make_float4(bf2f(au.x), bf2f(au.y), bf2f(au.z), bf2f(au.w));
            }
        }

#pragma unroll
        for (int s = 0; s < NPREV; ++s) {
            float w = earr[s * N_LOC + i] * inv_s[s];
            m.x = m.x * (1.f - w * er[s].x) + w * cd[s].x;
            m.y = m.y * (1.f - w * er[s].y) + w * cd[s].y;
            m.z = m.z * (1.f - w * er[s].z) + w * cd[s].z;
            m.w = m.w * (1.f - w * er[s].w) + w * cd[s].w;
        }

        float s = m.x * qc.x + m.y * qc.y + m.z * qc.z + m.w * qc.w;
        s += a4.x * qa.x + a4.y * qa.y + a4.z * qa.z + a4.w * qa.w;
        s += __shfl_xor(s, 1);
        s += __shfl_xor(s, 2);
        s += __shfl_xor(s, 4);
        s += __shfl_xor(s, 8);
        s += __shfl_xor(s, 16);
        float ev = __expf(beta * s);
        if (WRITE_E && lane == 0) enew[i] = ev;
        if (lane == 0) sumloc += ev;
        acc.x += ev * m.x; acc.y += ev * m.y;
        acc.z += ev * m.z; acc.w += ev * m.w;
    }

    __shared__ float sc[8][C];
    __shared__ float ssum[256];
    *(float4*)(&sc[rg][4 * lane]) = acc;
    ssum[threadIdx.x] = sumloc;
    __syncthreads();
    if (threadIdx.x < C) {
        float v = 0.f;
#pragma unroll
        for (int g = 0; g < 8; ++g) v += sc[g][threadIdx.x];
        part[blockIdx.x * 132 + threadIdx.x] = v;
    }
    for (int off = 128; off > 0; off >>= 1) {
        if (threadIdx.x < off) ssum[threadIdx.x] += ssum[threadIdx.x + off];
        __syncthreads();
    }
    if (threadIdx.x == 0) part[blockIdx.x * 132 + C] = ssum[0];
}

// ---------------------------------------------------------------------------
// Reduce GRID_BIG x 129 partials -> craw[0..128]; record softmax denominator.
// ---------------------------------------------------------------------------
__global__ __launch_bounds__(256) void reduce_part(
    const float* __restrict__ part, float* __restrict__ craw,
    float* __restrict__ ssum4, int step)
{
    const int j = blockIdx.x;           // 0..128
    float v = 0.f;
    for (int b = threadIdx.x; b < GRID_BIG; b += 256)
        v += part[b * 132 + j];
    __shared__ float sh[256];
    sh[threadIdx.x] = v;
    __syncthreads();
    for (int off = 128; off > 0; off >>= 1) {
        if (threadIdx.x < off) sh[threadIdx.x] += sh[threadIdx.x + off];
        __syncthreads();
    }
    if (threadIdx.x == 0) {
        craw[j] = sh[0];
        if (j == C) ssum4[step] = sh[0];
    }
}

// ---------------------------------------------------------------------------
// Once per launch: gix = x @ W_ih[0:128] + b_ih ; candx = x @ W_cand_x
// ---------------------------------------------------------------------------
__global__ __launch_bounds__(256) void prex(
    const float* __restrict__ x, const float* __restrict__ W_ih,
    const float* __restrict__ b_ih, const float* __restrict__ W_cx,
    float* __restrict__ gix, float* __restrict__ candx)
{
    const int tid = threadIdx.x;
    float a0 = 0.f, a1 = 0.f, a2 = 0.f, ac = 0.f;
    const int k0 = blockIdx.x * 8;
    for (int k = k0; k < k0 + 8; ++k) {
        float xk = x[k];
        const float* row = W_ih + (size_t)k * G3;
        a0 += xk * row[tid];
        a1 += xk * row[256 + tid];
        a2 += xk * row[512 + tid];
        if (tid < C) ac += xk * W_cx[k * C + tid];
    }
    const bool b0 = (blockIdx.x == 0);
    atomicAdd(gix + tid,        a0 + (b0 ? b_ih[tid] : 0.f));
    atomicAdd(gix + 256 + tid,  a1 + (b0 ? b_ih[256 + tid] : 0.f));
    atomicAdd(gix + 512 + tid,  a2 + (b0 ? b_ih[512 + tid] : 0.f));
    if (tid < C) atomicAdd(candx + tid, ac);
}

// ---------------------------------------------------------------------------
// Per step: raw erase/cand/query/sharpen projections from h.
// ---------------------------------------------------------------------------
__global__ __launch_bounds__(256) void post(
    const float* __restrict__ h,
    const float* __restrict__ W_er, const float* __restrict__ b_er,
    const float* __restrict__ W_ch, const float* __restrict__ b_cd,
    const float* __restrict__ W_q,  const float* __restrict__ b_q,
    const float* __restrict__ u_sh, const float* __restrict__ b_sh,
    const float* __restrict__ candx,
    float* __restrict__ eslot, float* __restrict__ cslot,
    float* __restrict__ qacc)
{
    const int tid = threadIdx.x;
    float ae = 0.f, ac = 0.f, aq = 0.f, ab = 0.f;
    const int k0 = blockIdx.x * 16;
    for (int k = k0; k < k0 + 16; ++k) {
        float hk = h[k];
        if (tid < C)  { ae += hk * W_er[k * C + tid]; ac += hk * W_ch[k * C + tid]; }
        if (tid < AC)   aq += hk * W_q[k * AC + tid];
        if (tid == 255) ab += hk * u_sh[k];
    }
    const bool b0 = (blockIdx.x == 0);
    if (tid < C) {
        atomicAdd(eslot + tid, ae + (b0 ? b_er[tid] : 0.f));
        atomicAdd(cslot + tid, ac + (b0 ? (candx[tid] + b_cd[tid]) : 0.f));
    }
    if (tid < AC)   atomicAdd(qacc + tid, aq + (b0 ? b_q[tid] : 0.f));
    if (tid == 255) atomicAdd(qacc + AC, ab + (b0 ? b_sh[0] : 0.f));
}

// ---------------------------------------------------------------------------
// Per step: GRU gate partials (16 k-sliced blocks) + last-arriving block
// reduces and applies the GRU combine -> hout. Zeroes qacc, resets counter.
// ---------------------------------------------------------------------------
__global__ __launch_bounds__(256) void gatesfin(
    const float* __restrict__ craw, const float* __restrict__ hprev,
    const float* __restrict__ W_ih, const float* __restrict__ W_hh,
    const float* __restrict__ b_hh, const float* __restrict__ gix,
    float* __restrict__ p2, float* __restrict__ hout,
    float* __restrict__ qacc, unsigned* __restrict__ counter)
{
    const int tid = threadIdx.x;
    const float inv = 1.0f / craw[C];
    float gi0 = 0.f, gi1 = 0.f, gi2 = 0.f, gh0 = 0.f, gh1 = 0.f, gh2 = 0.f;
    const int kc0 = blockIdx.x * 8;
    for (int k = kc0; k < kc0 + 8; ++k) {
        float ck = craw[k] * inv;                       // content[k]
        const float* row = W_ih + (size_t)(X + k) * G3;
        gi0 += ck * row[tid]; gi1 += ck * row[256 + tid]; gi2 += ck * row[512 + tid];
    }
    const int kh0 = blockIdx.x * 16;
    for (int k = kh0; k < kh0 + 16; ++k) {
        float hk = hprev[k];
        const float* row = W_hh + (size_t)k * G3;
        gh0 += hk * row[tid]; gh1 += hk * row[256 + tid]; gh2 += hk * row[512 + tid];
    }
    const bool b0 = (blockIdx.x == 0);
    float* pb = p2 + blockIdx.x * 1536;
    pb[tid]        = gi0 + (b0 ? gix[tid] : 0.f);
    pb[256 + tid]  = gi1 + (b0 ? gix[256 + tid] : 0.f);
    pb[512 + tid]  = gi2 + (b0 ? gix[512 + tid] : 0.f);
    pb[768 + tid]  = gh0 + (b0 ? b_hh[tid] : 0.f);
    pb[1024 + tid] = gh1 + (b0 ? b_hh[256 + tid] : 0.f);
    pb[1280 + tid] = gh2 + (b0 ? b_hh[512 + tid] : 0.f);
    __threadfence();
    __syncthreads();
    __shared__ int lastBlk;
    if (tid == 0) lastBlk = (atomicAdd(counter, 1u) == 15u) ? 1 : 0;
    __syncthreads();
    if (!lastBlk) return;
    __threadfence();
    float ir = 0.f, iz = 0.f, in_ = 0.f, hr = 0.f, hz = 0.f, hn = 0.f;
    for (int b = 0; b < 16; ++b) {
        const float* q = p2 + b * 1536;
        ir += q[tid]; iz += q[256 + tid]; in_ += q[512 + tid];
        hr += q[768 + tid]; hz += q[1024 + tid]; hn += q[1280 + tid];
    }
    float r = sigmoidf_(ir + hr);
    float z = sigmoidf_(iz + hz);
    float n = tanhf(in_ + r * hn);
    hout[tid] = (1.f - z) * n + z * hprev[tid];
    if (tid < 160) qacc[tid] = 0.f;
    if (tid == 0) *counter = 0u;
}

extern "C" void kernel_launch(void* const* d_in, const int* in_sizes, int n_in,
                              void* d_out, int out_size, void* d_ws, size_t ws_size,
                              hipStream_t stream) {
    (void)in_sizes; (void)n_in; (void)out_size; (void)ws_size;
    const float* x    = (const float*)d_in[0];
    const float* h0   = (const float*)d_in[1];
    const float* mem0 = (const float*)d_in[2];   // read-only
    const float* addr = (const float*)d_in[3];
    const float* W_q  = (const float*)d_in[4];
    const float* b_q  = (const float*)d_in[5];
    const float* u_sh = (const float*)d_in[6];
    const float* b_sh = (const float*)d_in[7];
    const float* W_er = (const float*)d_in[8];
    const float* b_er = (const float*)d_in[9];
    const float* W_ch = (const float*)d_in[10];
    const float* W_cx = (const float*)d_in[11];
    const float* b_cd = (const float*)d_in[12];
    const float* W_ih = (const float*)d_in[13];
    const float* W_hh = (const float*)d_in[14];
    const float* b_ih = (const float*)d_in[15];
    const float* b_hh = (const float*)d_in[16];
    float* hout = (float*)d_out;

    // workspace layout:
    float*    e      = (float*)d_ws;                       // [3][N_LOC] fp32
    ushort_t* membf  = (ushort_t*)(e + 3 * N_LOC);         // [N_LOC][C] bf16
    ushort_t* addrbf = membf + (size_t)N_LOC * C;          // [N_LOC][A] bf16
    float*    part   = (float*)(addrbf + (size_t)N_LOC * A); // [GRID_BIG][132]
    float*    S      = part + GRID_BIG * 132;
    float*    craw   = S;                                  // [144]
    float*    qacc   = S + 144;                            // [160] (153 used)
    float*    ehist  = S + 304;                            // [4][128]
    float*    chist  = S + 816;                            // [4][128]
    float*    gix    = S + 1328;                           // [768]
    float*    candx  = S + 2096;                           // [128]
    float*    ssum4  = S + 2224;                           // [8]
    unsigned* counter= (unsigned*)(S + 2232);              // [1] (+pad)
    float*    p2     = S + 2240;                           // [16][1536]

    hipMemsetAsync(S, 0, 2240 * sizeof(float), stream);
    prex<<<16, 256, 0, stream>>>(x, W_ih, b_ih, W_cx, gix, candx);
    post<<<16, 256, 0, stream>>>(h0, W_er, b_er, W_ch, b_cd, W_q, b_q, u_sh, b_sh,
                                 candx, ehist, chist, qacc);
    // step 1 (also emits bf16 copies of mem0/addr)
    big_pass<0, true, true><<<GRID_BIG, 256, 0, stream>>>(
        mem0, addr, membf, addrbf, qacc, ehist, chist, ssum4, e, e, part);
    reduce_part<<<129, 256, 0, stream>>>(part, craw, ssum4, 1);
    gatesfin<<<16, 256, 0, stream>>>(craw, h0, W_ih, W_hh, b_hh, gix, p2, hout,
                                     qacc, counter);
    post<<<16, 256, 0, stream>>>(hout, W_er, b_er, W_ch, b_cd, W_q, b_q, u_sh, b_sh,
                                 candx, ehist + C, chist + C, qacc);
    // step 2
    big_pass<1, true, false><<<GRID_BIG, 256, 0, stream>>>(
        mem0, addr, membf, addrbf, qacc, ehist, chist, ssum4, e, e + N_LOC, part);
    reduce_part<<<129, 256, 0, stream>>>(part, craw, ssum4, 2);
    gatesfin<<<16, 256, 0, stream>>>(craw, hout, W_ih, W_hh, b_hh, gix, p2, hout,
                                     qacc, counter);
    post<<<16, 256, 0, stream>>>(hout, W_er, b_er, W_ch, b_cd, W_q, b_q, u_sh, b_sh,
                                 candx, ehist + 2 * C, chist + 2 * C, qacc);
    // step 3
    big_pass<2, true, false><<<GRID_BIG, 256, 0, stream>>>(
        mem0, addr, membf, addrbf, qacc, ehist, chist, ssum4, e, e + 2 * N_LOC, part);
    reduce_part<<<129, 256, 0, stream>>>(part, craw, ssum4, 3);
    gatesfin<<<16, 256, 0, stream>>>(craw, hout, W_ih, W_hh, b_hh, gix, p2, hout,
                                     qacc, counter);
    post<<<16, 256, 0, stream>>>(hout, W_er, b_er, W_ch, b_cd, W_q, b_q, u_sh, b_sh,
                                 candx, ehist + 3 * C, chist + 3 * C, qacc);
    // step 4 (no memory write-back needed; e not stored)
    big_pass<3, false, false><<<GRID_BIG, 256, 0, stream>>>(
        mem0, addr, membf, addrbf, qacc, ehist, chist, ssum4, e, e, part);
    reduce_part<<<129, 256, 0, stream>>>(part, craw, ssum4, 4);
    gatesfin<<<16, 256, 0, stream>>>(craw, hout, W_ih, W_hh, b_hh, gix, p2, hout,
                                     qacc, counter);
}